// Round 18
// baseline (930.384 us; speedup 1.0000x reference)
//
#include <hip/hip_runtime.h>
#include <stdint.h>

// Problem dims
#define R_ 8
#define B_ 16
#define S_ 512
#define H_ 1024
#define E_ 32
#define P_ 4
#define M_ (B_*S_)          // 8192

// fused grid: 16 roles + 112 ENT + 128 TOK + 256 SR = 512 blocks x 512 thr,
// 64KB LDS/block -> exactly 2 blocks/CU -> all resident at launch.
#define ROLB_ 16
#define ENTB_ 112
#define TOKB_ 128
#define SRB_  256
// bar layout: [0..7] srdone[slice], [8] tokdone, [9] entdone, [10..16] role barriers
#define SR_SIG_   2048      // 2048 SR waves signal each slice
#define TOK_SIG_  1024      // 1024 TOK waves
#define ENT_SIG_  896       // 896 ENT waves

__device__ __forceinline__ float dot4(float4 a, float4 b){
  return a.x*b.x + a.y*b.y + a.z*b.z + a.w*b.w;
}

__device__ __forceinline__ void group_barrier(int* cnt, int nblk){
  __syncthreads();
  if (threadIdx.x == 0){
    __threadfence();
    __hip_atomic_fetch_add(cnt, 1, __ATOMIC_RELEASE, __HIP_MEMORY_SCOPE_AGENT);
    while (__hip_atomic_load(cnt, __ATOMIC_ACQUIRE, __HIP_MEMORY_SCOPE_AGENT) < nblk)
      __builtin_amdgcn_s_sleep(8);
    __threadfence();
  }
  __syncthreads();
}

// ---------------- vec chain (R16-validated, 7 serial dispatches) ----------
__global__ __launch_bounds__(256) void vec_chain_kernel(
    int k, const float* __restrict__ aw, const float* __restrict__ ab,
    const float* __restrict__ sw, const float* __restrict__ mw,
    float* __restrict__ a_s, float* __restrict__ a_m,
    float* __restrict__ V, float* __restrict__ betas)
{
  int w = (int)((blockIdx.x * blockDim.x + threadIdx.x) >> 6);
  int lane = threadIdx.x & 63;
  const float* as_k = (k == 0) ? (sw + 2*H_) : (a_s + (size_t)k*H_);
  const float* am_k = (k == 0) ? (mw + 2*H_) : (a_m + (size_t)k*H_);
  if (w < H_){
    const float* w1 = aw + (size_t)w * H_;
    const float* w2 = aw + (size_t)(H_ + w) * H_;
    float vs = 0.f, vm = 0.f, ns = 0.f, nm = 0.f;
    #pragma unroll
    for (int i = 0; i < 4; i++){
      int c = i*256 + lane*4;
      float4 r1 = *(const float4*)(w1 + c);
      float4 r2 = *(const float4*)(w2 + c);
      float4 xs = *(const float4*)(as_k + c);
      float4 xm = *(const float4*)(am_k + c);
      vs += dot4(r1, xs); vm += dot4(r1, xm);
      ns += dot4(r2, xs); nm += dot4(r2, xm);
    }
    #pragma unroll
    for (int m = 32; m >= 1; m >>= 1){
      vs += __shfl_xor(vs, m, 64); vm += __shfl_xor(vm, m, 64);
      ns += __shfl_xor(ns, m, 64); nm += __shfl_xor(nm, m, 64);
    }
    if (lane == 0){
      V[(size_t)k*H_ + w]       = vs;
      V[(size_t)(7 + k)*H_ + w] = vm;
      a_s[(size_t)(k+1)*H_ + w] = ns;
      a_m[(size_t)(k+1)*H_ + w] = nm;
    }
  } else if (w == H_ || w == H_ + 1){
    const float* av = (w == H_) ? as_k : am_k;
    float d = 0.f;
    #pragma unroll
    for (int i = 0; i < 4; i++){
      int c = i*256 + lane*4;
      d += dot4(*(const float4*)(ab + c), *(const float4*)(av + c));
    }
    #pragma unroll
    for (int m = 32; m >= 1; m >>= 1) d += __shfl_xor(d, m, 64);
    if (lane == 0) betas[(w == H_ ? 0 : 8) + k] = d;
  }
}

// ---------------- fused: roles(gated) || ENT+init || TOK || SR ----------
__global__ __launch_bounds__(512) void fused_kernel(
    const float* __restrict__ sr, const float* __restrict__ tok,
    const float* __restrict__ ent, const float* __restrict__ sw,
    const float* __restrict__ mw, const float* __restrict__ V,
    const float* __restrict__ tmask, const float* __restrict__ betas,
    const float* __restrict__ sb, const float* __restrict__ mb,
    const int* __restrict__ c2t, const int* __restrict__ e2t,
    const int* __restrict__ spans, const int* __restrict__ labels,
    float* __restrict__ sr_s, float* __restrict__ sr_m,
    float* __restrict__ tok_s, float* __restrict__ ent_m,
    float* __restrict__ G, float* __restrict__ PS,
    float* __restrict__ msum, float* __restrict__ out,
    float* __restrict__ xlog, int* bar)
{
  __shared__ float lds[16384];      // 64KB: SR staging / roles scratch
  const int blk  = blockIdx.x;
  const int t    = threadIdx.x;
  const int lane = t & 63;
  const int w8   = t >> 6;          // wave 0..7
  const int co   = lane * 4;

  if (blk >= ROLB_ + ENTB_ + TOKB_){
    // ================= SR: 256 blocks x 8 waves, 32 rows/wave =================
    const int wid = (blk - ROLB_ - ENTB_ - TOKB_)*8 + w8;   // 0..2047
    float4 ws4[4], wm4[4];
    #pragma unroll
    for (int i = 0; i < 4; i++){
      ws4[i] = *(const float4*)(sw + i*256 + co);
      wm4[i] = *(const float4*)(mw + i*256 + co);
    }
    float* mybuf = lds + w8*2048;   // 2 bufs x 1024 floats
    auto STAGE = [&](int bufI, int p){
      const float* gb = sr + (size_t)(p*2048 + wid) * H_;
      float* lb = mybuf + bufI*1024;
      #pragma unroll
      for (int pp = 0; pp < 4; ++pp){
        __builtin_amdgcn_global_load_lds(
            (const __attribute__((address_space(1))) unsigned int*)(gb + pp*256 + lane*4),
            (__attribute__((address_space(3))) unsigned int*)(lb + pp*256), 16, 0, 0);
      }
    };
    STAGE(0, 0);
    for (int p = 0; p < 32; ++p){
      if (p < 31){
        STAGE((p + 1) & 1, p + 1);
        asm volatile("s_waitcnt vmcnt(4)" ::: "memory");
      } else {
        asm volatile("s_waitcnt vmcnt(0)" ::: "memory");
      }
      const float* lrow = mybuf + (p & 1)*1024;
      float a0 = 0.f, a1 = 0.f;
      #pragma unroll
      for (int i = 0; i < 4; i++){
        float4 v = *(const float4*)(lrow + i*256 + co);
        a0 += dot4(v, ws4[i]);
        a1 += dot4(v, wm4[i]);
      }
      #pragma unroll
      for (int m = 32; m >= 1; m >>= 1){
        a0 += __shfl_xor(a0,m,64); a1 += __shfl_xor(a1,m,64);
      }
      int row = p*2048 + wid;
      if (lane == 0){
        sr_s[row] = a0; sr_m[row] = a1;
        if ((p & 3) == 3)   // slice (p>>2) complete for this wave
          __hip_atomic_fetch_add(&bar[p >> 2], 1, __ATOMIC_RELEASE, __HIP_MEMORY_SCOPE_AGENT);
      }
    }
  } else if (blk >= ROLB_ + ENTB_){
    // ================= TOK: 128 blocks x 8 waves, parity split =================
    const int gw = (blk - ROLB_ - ENTB_)*8 + w8;   // 0..1023
    const int h  = gw & 1;
    const int r0 = gw >> 1;                        // 0..511
    if (h == 0){
      for (int it = 0; it < 16; ++it){
        int rr = r0 + it*512;
        const float* rp = tok + (size_t)rr * H_;
        float acc[8];
        #pragma unroll
        for (int q = 0; q < 8; q++) acc[q] = 0.f;
        #pragma unroll
        for (int i = 0; i < 4; i++){
          int c = i*256 + co;
          float4 v = *(const float4*)(rp + c);
          acc[0] += dot4(v, *(const float4*)(sw + H_ + c));
          #pragma unroll
          for (int q = 0; q < 7; q++)
            acc[q+1] += dot4(v, *(const float4*)(V + (size_t)q*H_ + c));
        }
        #pragma unroll
        for (int m = 32; m >= 1; m >>= 1)
          #pragma unroll
          for (int q = 0; q < 8; q++) acc[q] += __shfl_xor(acc[q],m,64);
        if (lane == 0){
          tok_s[rr] = acc[0];
          #pragma unroll
          for (int q = 0; q < 7; q++) G[(size_t)q*M_ + rr] = acc[q+1];
        }
      }
    } else {
      for (int it = 0; it < 16; ++it){
        int rr = r0 + it*512;
        const float* rp = tok + (size_t)rr * H_;
        float acc[7];
        #pragma unroll
        for (int q = 0; q < 7; q++) acc[q] = 0.f;
        #pragma unroll
        for (int i = 0; i < 4; i++){
          int c = i*256 + co;
          float4 v = *(const float4*)(rp + c);
          #pragma unroll
          for (int q = 0; q < 7; q++)
            acc[q] += dot4(v, *(const float4*)(V + (size_t)(7+q)*H_ + c));
        }
        #pragma unroll
        for (int m = 32; m >= 1; m >>= 1)
          #pragma unroll
          for (int q = 0; q < 7; q++) acc[q] += __shfl_xor(acc[q],m,64);
        if (lane == 0){
          #pragma unroll
          for (int q = 0; q < 7; q++) G[(size_t)(7+q)*M_ + rr] = acc[q];
        }
      }
    }
    if (lane == 0)
      __hip_atomic_fetch_add(&bar[8], 1, __ATOMIC_RELEASE, __HIP_MEMORY_SCOPE_AGENT);
  } else if (blk >= ROLB_){
    // ================= ENT + PS-zero + masksum: 112 blocks x 8 waves =================
    const int eb = blk - ROLB_;                    // 0..111
    const int gt = eb*512 + t;
    if (gt < 32768) ((float4*)PS)[gt] = make_float4(0.f,0.f,0.f,0.f);
    if (eb == 0 && w8 == 0){
      float s = 0.f;
      #pragma unroll
      for (int i = 0; i < 32; i++){
        float4 v = ((const float4*)tmask)[i*64 + lane];
        s += v.x + v.y + v.z + v.w;
      }
      #pragma unroll
      for (int m = 32; m >= 1; m >>= 1) s += __shfl_xor(s, m, 64);
      if (lane == 0){ msum[0] = s; out[0] = 0.f; }
    }
    const int ew = eb*8 + w8;                      // 0..895
    float4 wmh[4];
    #pragma unroll
    for (int i = 0; i < 4; i++) wmh[i] = *(const float4*)(mw + H_ + i*256 + co);
    for (int rr = ew; rr < B_*S_; rr += ENT_SIG_){
      const float* rp = ent + (size_t)rr * H_;
      float a0 = 0.f;
      #pragma unroll
      for (int i = 0; i < 4; i++)
        a0 += dot4(*(const float4*)(rp + i*256 + co), wmh[i]);
      #pragma unroll
      for (int m = 32; m >= 1; m >>= 1) a0 += __shfl_xor(a0,m,64);
      if (lane == 0) ent_m[rr] = a0;
    }
    if (lane == 0)
      __hip_atomic_fetch_add(&bar[9], 1, __ATOMIC_RELEASE, __HIP_MEMORY_SCOPE_AGENT);
  } else {
    // ================= ROLES: 16 blocks x 512 thr, slice-gated =================
    float* pta    = lds;            // [512]
    float* merged = lds + 512;      // [512]
    float* es     = lds + 1024;     // [32]
    float* red    = lds + 1056;     // [8]
    int*   spn    = (int*)(lds + 1064);   // [256]
    const int b = blk;
    const int bs = b*S_ + t;
    const int wid2 = t >> 6;

    if (t < E_*P_*2) spn[t] = spans[b*(E_*P_*2) + t];
    const int c_own = c2t[bs];
    const int e_own = e2t[bs];
    const float sb0 = sb[0], mb0 = mb[0];

    // start gate: ENT(+PS,msum,out) + TOK(G,tok_s) + SR slice 0
    if (t == 0){
      while (__hip_atomic_load(&bar[9], __ATOMIC_ACQUIRE, __HIP_MEMORY_SCOPE_AGENT) < ENT_SIG_ ||
             __hip_atomic_load(&bar[8], __ATOMIC_ACQUIRE, __HIP_MEMORY_SCOPE_AGENT) < TOK_SIG_ ||
             __hip_atomic_load(&bar[0], __ATOMIC_ACQUIRE, __HIP_MEMORY_SCOPE_AGENT) < SR_SIG_)
        __builtin_amdgcn_s_sleep(16);
      __threadfence();
    }
    __syncthreads();

    const float msumv = msum[0];
    const float tok_sv = tok_s[bs], ent_mv = ent_m[bs];
    float bsum_s = 0.f, bsum_m = 0.f;

    for (int r = 0; r < R_; ++r){
      pta[t] = 0.f;
      if (t < E_) es[t] = 0.f;

      float sl[B_], ml[B_];
      if (r == 0){
        #pragma unroll
        for (int bb = 0; bb < B_; bb++){
          int q = bb*S_ + t;
          sl[bb] = sr_s[q] + tok_s[q] + sb0;
          ml[bb] = sr_m[q] + ent_m[q] + mb0;
        }
      } else {
        const float* xc = xlog + (size_t)(r & 1) * (2*M_);
        #pragma unroll
        for (int bb = 0; bb < B_; bb++){
          sl[bb] = xc[bb*S_ + t];
          ml[bb] = xc[M_ + bb*S_ + t];
        }
      }
      float smax = -1e30f, mmax = -1e30f;
      #pragma unroll
      for (int bb = 0; bb < B_; bb++){ smax = fmaxf(smax, sl[bb]); mmax = fmaxf(mmax, ml[bb]); }
      float ssum = 0.f, msv = 0.f;
      #pragma unroll
      for (int bb = 0; bb < B_; bb++){ ssum += __expf(sl[bb]-smax); msv += __expf(ml[bb]-mmax); }
      float spv = __expf(sl[b]-smax) / ssum;
      float mpv = __expf(ml[b]-mmax) / msv;

      __syncthreads();
      if (c_own >= 0) atomicAdd(&pta[c_own], spv);
      if (e_own >= 0) atomicAdd(&es[e_own], mpv);
      __syncthreads();

      float pei = 0.f;
      #pragma unroll
      for (int e = 0; e < E_; e++){
        float sc = es[e];
        #pragma unroll
        for (int p = 0; p < P_; p++){
          int st = spn[e*8 + p*2], en = spn[e*8 + p*2 + 1];
          if (t >= st && t < en) pei += sc;
        }
      }
      float mg = fmaxf(pta[t], pei);
      merged[t] = mg;
      out[1 + (size_t)r*M_ + bs] = mg;
      __syncthreads();

      float ah_r = (c_own >= 0) ? merged[c_own] : 0.f;

      float mx = mg;
      #pragma unroll
      for (int k = 32; k >= 1; k >>= 1) mx = fmaxf(mx, __shfl_xor(mx, k, 64));
      if (lane == 0) red[wid2] = mx;
      __syncthreads();
      float gmx = red[0];
      #pragma unroll
      for (int i = 1; i < 8; i++) gmx = fmaxf(gmx, red[i]);
      float se = __expf(mg - gmx);
      #pragma unroll
      for (int k = 32; k >= 1; k >>= 1) se += __shfl_xor(se, k, 64);
      __syncthreads();
      if (lane == 0) red[wid2] = se;
      __syncthreads();
      if (t == 0){
        float tot = 0.f;
        #pragma unroll
        for (int i = 0; i < 8; i++) tot += red[i];
        float lse = gmx + __logf(tot);
        int lbl = labels[r*B_ + b];
        float nll = lse - merged[lbl];
        atomicAdd(out, nll * msumv * (1.0f/16.0f));
      }

      if (r < 7){
        // gate: SR slice r+1 written before reading it in the handoff
        if (t == 0){
          while (__hip_atomic_load(&bar[r+1], __ATOMIC_ACQUIRE, __HIP_MEMORY_SCOPE_AGENT) < SR_SIG_)
            __builtin_amdgcn_s_sleep(16);
          __threadfence();
        }
        __syncthreads();

        bsum_s += betas[r]; bsum_m += betas[8 + r];
        float ps_next = 0.f, pm_next = 0.f;
        for (int q = r + 1; q <= 7; q++){
          float gs = G[(size_t)(q-1-r)*M_ + bs];
          float gm = G[(size_t)(7 + q-1-r)*M_ + bs];
          float ns = PS[((size_t)q*2 + 0)*M_ + bs] + ah_r * gs;
          float nm = PS[((size_t)q*2 + 1)*M_ + bs] + ah_r * gm;
          PS[((size_t)q*2 + 0)*M_ + bs] = ns;
          PS[((size_t)q*2 + 1)*M_ + bs] = nm;
          if (q == r + 1){ ps_next = ns; pm_next = nm; }
        }
        float xn = sr_s[(size_t)((r+1)*B_ + b)*S_ + t] + tok_sv + ps_next + sb0 + bsum_s;
        float yn = sr_m[(size_t)((r+1)*B_ + b)*S_ + t] + ent_mv + pm_next + mb0 + bsum_m;
        float* xn_buf = xlog + (size_t)((r+1) & 1) * (2*M_);
        xn_buf[bs] = xn;
        xn_buf[M_ + bs] = yn;
        group_barrier(&bar[10 + r], ROLB_);   // separates write from next-role read
      }
    }
  }
}

extern "C" void kernel_launch(void* const* d_in, const int* in_sizes, int n_in,
                              void* d_out, int out_size, void* d_ws, size_t ws_size,
                              hipStream_t stream){
  (void)in_sizes; (void)n_in; (void)out_size; (void)ws_size;
  const int*   labels = (const int*)  d_in[0];
  const float* sr     = (const float*)d_in[1];
  const float* tok    = (const float*)d_in[2];
  const float* ent    = (const float*)d_in[3];
  const float* tmask  = (const float*)d_in[4];
  // d_in[5] entity_mask unused by reference
  const int*   spans  = (const int*)  d_in[6];
  const int*   c2t    = (const int*)  d_in[7];
  const int*   e2t    = (const int*)  d_in[8];
  const float* sw     = (const float*)d_in[9];
  const float* sb     = (const float*)d_in[10];
  const float* mw     = (const float*)d_in[11];
  const float* mb     = (const float*)d_in[12];
  const float* aw     = (const float*)d_in[13];
  const float* ab     = (const float*)d_in[14];
  float* out = (float*)d_out;
  char*  ws  = (char*)d_ws;

  size_t o = 0;
  auto take = [&](size_t bytes){ size_t c = o; o += (bytes + 255) & ~(size_t)255; return c; };
  float* sr_s  = (float*)(ws + take((size_t)R_*B_*S_*4));
  float* sr_m  = (float*)(ws + take((size_t)R_*B_*S_*4));
  float* tok_s = (float*)(ws + take((size_t)B_*S_*4));
  float* ent_m = (float*)(ws + take((size_t)B_*S_*4));
  float* a_s   = (float*)(ws + take((size_t)8*H_*4));
  float* a_m   = (float*)(ws + take((size_t)8*H_*4));
  float* V     = (float*)(ws + take((size_t)14*H_*4));
  float* betas = (float*)(ws + take(64));
  float* G     = (float*)(ws + take((size_t)14*M_*4));
  float* PS    = (float*)(ws + take((size_t)8*2*M_*4));   // zeroed in ENT section
  float* xlog  = (float*)(ws + take((size_t)2*2*M_*4));
  float* msum  = (float*)(ws + take(256));
  int*   bar   = (int*)  (ws + take(128));                // 17 counters

  hipMemsetAsync(bar, 0, 128, stream);
  for (int k = 0; k < 7; k++)
    vec_chain_kernel<<<257, 256, 0, stream>>>(k, aw, ab, sw, mw, a_s, a_m, V, betas);
  fused_kernel<<<ROLB_ + ENTB_ + TOKB_ + SRB_, 512, 0, stream>>>(
      sr, tok, ent, sw, mw, V, tmask, betas, sb, mb, c2t, e2t, spans, labels,
      sr_s, sr_m, tok_s, ent_m, G, PS, msum, out, xlog, bar);
}

// Round 20
// 168.986 us; speedup vs baseline: 5.5057x; 5.5057x over previous
//
#include <hip/hip_runtime.h>
#include <stdint.h>

// Problem dims
#define R_ 8
#define B_ 16
#define S_ 512
#define H_ 1024
#define E_ 32
#define P_ 4
#define M_ (B_*S_)          // 8192
#define SRB2_ 1024          // SR staging blocks
#define TOKB_ 512
#define ENTB_ 512

#define NT_AUX_ 2           // gfx950 CPol NT bit for global_load_lds aux

typedef float v4f __attribute__((ext_vector_type(4)));

__device__ __forceinline__ float dot4(float4 a, float4 b){
  return a.x*b.x + a.y*b.y + a.z*b.z + a.w*b.w;
}
__device__ __forceinline__ float dot4v(v4f a, float4 b){
  return a.x*b.x + a.y*b.y + a.z*b.z + a.w*b.w;
}
__device__ __forceinline__ v4f ldnt4(const float* p){
  return __builtin_nontemporal_load((const v4f*)p);
}

// per-instance counter barrier (small groups ONLY; >=1024 spinners catastrophic — R10;
// multi-producer signaling into one line catastrophic — R18)
__device__ __forceinline__ void group_barrier(int* cnt, int nblk){
  __syncthreads();
  if (threadIdx.x == 0){
    __threadfence();
    __hip_atomic_fetch_add(cnt, 1, __ATOMIC_RELEASE, __HIP_MEMORY_SCOPE_AGENT);
    while (__hip_atomic_load(cnt, __ATOMIC_ACQUIRE, __HIP_MEMORY_SCOPE_AGENT) < nblk)
      __builtin_amdgcn_s_sleep(8);
    __threadfence();
  }
  __syncthreads();
}

// ---------------- vec chain: a_{k+1} = W2 a_k, V[k] = W1 a_k, beta_k = ab.a_k ----
__global__ __launch_bounds__(256) void vec_chain_kernel(
    int k, const float* __restrict__ aw, const float* __restrict__ ab,
    const float* __restrict__ sw, const float* __restrict__ mw,
    float* __restrict__ a_s, float* __restrict__ a_m,
    float* __restrict__ V, float* __restrict__ betas)
{
  int w = (int)((blockIdx.x * blockDim.x + threadIdx.x) >> 6);
  int lane = threadIdx.x & 63;
  const float* as_k = (k == 0) ? (sw + 2*H_) : (a_s + (size_t)k*H_);
  const float* am_k = (k == 0) ? (mw + 2*H_) : (a_m + (size_t)k*H_);
  if (w < H_){
    const float* w1 = aw + (size_t)w * H_;
    const float* w2 = aw + (size_t)(H_ + w) * H_;
    float vs = 0.f, vm = 0.f, ns = 0.f, nm = 0.f;
    #pragma unroll
    for (int i = 0; i < 4; i++){
      int c = i*256 + lane*4;
      float4 r1 = *(const float4*)(w1 + c);
      float4 r2 = *(const float4*)(w2 + c);
      float4 xs = *(const float4*)(as_k + c);
      float4 xm = *(const float4*)(am_k + c);
      vs += dot4(r1, xs); vm += dot4(r1, xm);
      ns += dot4(r2, xs); nm += dot4(r2, xm);
    }
    #pragma unroll
    for (int m = 32; m >= 1; m >>= 1){
      vs += __shfl_xor(vs, m, 64); vm += __shfl_xor(vm, m, 64);
      ns += __shfl_xor(ns, m, 64); nm += __shfl_xor(nm, m, 64);
    }
    if (lane == 0){
      V[(size_t)k*H_ + w]       = vs;
      V[(size_t)(7 + k)*H_ + w] = vm;
      a_s[(size_t)(k+1)*H_ + w] = ns;
      a_m[(size_t)(k+1)*H_ + w] = nm;
    }
  } else if (w == H_ || w == H_ + 1){
    const float* av = (w == H_) ? as_k : am_k;
    float d = 0.f;
    #pragma unroll
    for (int i = 0; i < 4; i++){
      int c = i*256 + lane*4;
      d += dot4(*(const float4*)(ab + c), *(const float4*)(av + c));
    }
    #pragma unroll
    for (int m = 32; m >= 1; m >>= 1) d += __shfl_xor(d, m, 64);
    if (lane == 0) betas[(w == H_ ? 0 : 8) + k] = d;
  }
}

// ---------------- dots: R16 structure + NT streaming loads ----
__global__ __launch_bounds__(256) void dots_staged_kernel(
    const float* __restrict__ sr, const float* __restrict__ tok,
    const float* __restrict__ ent, const float* __restrict__ sw,
    const float* __restrict__ mw, const float* __restrict__ V,
    const float* __restrict__ tmask,
    float* __restrict__ sr_s, float* __restrict__ sr_m,
    float* __restrict__ tok_s, float* __restrict__ ent_m,
    float* __restrict__ G, float* __restrict__ PS,
    float* __restrict__ msum, float* __restrict__ out)
{
  __shared__ float lds[8*1024];     // 2 bufs x 4 rows x 1024 = 32 KB
  const int blk  = blockIdx.x;
  const int lane = threadIdx.x & 63;
  const int lw   = threadIdx.x >> 6;
  const int co   = lane * 4;

  if (blk < SRB2_){
    // ---- SR: per-wave dbuf pipeline, NT global_load_lds (single-use stream) ----
    float4 ws4[4], wm4[4];
    #pragma unroll
    for (int i = 0; i < 4; i++){
      ws4[i] = *(const float4*)(sw + i*256 + co);
      wm4[i] = *(const float4*)(mw + i*256 + co);
    }
    auto STAGE = [&](int bufI, int h){
      int row = (blk + (h >> 1)*SRB2_)*8 + (h & 1)*4 + lw;
      const float* gb = sr + (size_t)row * H_;
      float* lb = lds + bufI*4096 + lw*1024;
      #pragma unroll
      for (int p = 0; p < 4; ++p){
        __builtin_amdgcn_global_load_lds(
            (const __attribute__((address_space(1))) unsigned int*)(gb + p*256 + lane*4),
            (__attribute__((address_space(3))) unsigned int*)(lb + p*256), 16, 0, NT_AUX_);
      }
    };
    STAGE(0, 0);
    for (int h = 0; h < 16; ++h){
      if (h < 15){
        STAGE((h + 1) & 1, h + 1);
        if (h == 0) asm volatile("s_waitcnt vmcnt(4)" ::: "memory");
        else        asm volatile("s_waitcnt vmcnt(6)" ::: "memory");
      } else {
        asm volatile("s_waitcnt vmcnt(0)" ::: "memory");
      }
      const float* lrow = lds + (h & 1)*4096 + lw*1024;
      float a0 = 0.f, a1 = 0.f;
      #pragma unroll
      for (int i = 0; i < 4; i++){
        float4 v = *(const float4*)(lrow + i*256 + co);
        a0 += dot4(v, ws4[i]);
        a1 += dot4(v, wm4[i]);
      }
      #pragma unroll
      for (int m = 32; m >= 1; m >>= 1){
        a0 += __shfl_xor(a0,m,64); a1 += __shfl_xor(a1,m,64);
      }
      int row = (blk + (h >> 1)*SRB2_)*8 + (h & 1)*4 + lw;
      if (lane == 0){ sr_s[row] = a0; sr_m[row] = a1; }
    }
  } else if (blk < SRB2_ + TOKB_){
    // ---- TOK: parity split; NT loads for tok rows (single-use); V cached ----
    const int gw = (blk - SRB2_)*4 + lw;          // 0..2047
    const int h  = gw & 1;
    const int r0 = gw >> 1;                       // 0..1023
    if (h == 0){
      for (int it = 0; it < 8; ++it){
        int rr = r0 + it*1024;
        const float* rp = tok + (size_t)rr * H_;
        float acc[8];
        #pragma unroll
        for (int q = 0; q < 8; q++) acc[q] = 0.f;
        #pragma unroll
        for (int i = 0; i < 4; i++){
          int c = i*256 + co;
          v4f v = ldnt4(rp + c);
          acc[0] += dot4v(v, *(const float4*)(sw + H_ + c));
          #pragma unroll
          for (int q = 0; q < 7; q++)
            acc[q+1] += dot4v(v, *(const float4*)(V + (size_t)q*H_ + c));
        }
        #pragma unroll
        for (int m = 32; m >= 1; m >>= 1)
          #pragma unroll
          for (int q = 0; q < 8; q++) acc[q] += __shfl_xor(acc[q],m,64);
        if (lane == 0){
          tok_s[rr] = acc[0];
          #pragma unroll
          for (int q = 0; q < 7; q++) G[(size_t)q*M_ + rr] = acc[q+1];
        }
      }
    } else {
      for (int it = 0; it < 8; ++it){
        int rr = r0 + it*1024;
        const float* rp = tok + (size_t)rr * H_;
        float acc[7];
        #pragma unroll
        for (int q = 0; q < 7; q++) acc[q] = 0.f;
        #pragma unroll
        for (int i = 0; i < 4; i++){
          int c = i*256 + co;
          v4f v = ldnt4(rp + c);
          #pragma unroll
          for (int q = 0; q < 7; q++)
            acc[q] += dot4v(v, *(const float4*)(V + (size_t)(7+q)*H_ + c));
        }
        #pragma unroll
        for (int m = 32; m >= 1; m >>= 1)
          #pragma unroll
          for (int q = 0; q < 7; q++) acc[q] += __shfl_xor(acc[q],m,64);
        if (lane == 0){
          #pragma unroll
          for (int q = 0; q < 7; q++) G[(size_t)(7+q)*M_ + rr] = acc[q];
        }
      }
    }
  } else {
    // ---- ENT + INIT: NT loads for ent rows ----
    const int eb = blk - SRB2_ - TOKB_;           // 0..511
    const int gt = eb*256 + threadIdx.x;
    if (gt < 32768) ((float4*)PS)[gt] = make_float4(0.f,0.f,0.f,0.f);
    if (eb == 0 && lw == 0){
      float s = 0.f;
      #pragma unroll
      for (int i = 0; i < 32; i++){
        float4 v = ((const float4*)tmask)[i*64 + lane];
        s += v.x + v.y + v.z + v.w;
      }
      #pragma unroll
      for (int m = 32; m >= 1; m >>= 1) s += __shfl_xor(s, m, 64);
      if (lane == 0){ msum[0] = s; out[0] = 0.f; }
    }
    const int ew = eb*4 + lw;                     // 0..2047
    float4 wmh[4];
    #pragma unroll
    for (int i = 0; i < 4; i++) wmh[i] = *(const float4*)(mw + H_ + i*256 + co);
    #pragma unroll
    for (int it = 0; it < 4; ++it){
      int rr = ew + it*2048;
      const float* rp = ent + (size_t)rr * H_;
      float a0 = 0.f;
      #pragma unroll
      for (int i = 0; i < 4; i++)
        a0 += dot4v(ldnt4(rp + i*256 + co), wmh[i]);
      #pragma unroll
      for (int m = 32; m >= 1; m >>= 1) a0 += __shfl_xor(a0,m,64);
      if (lane == 0) ent_m[rr] = a0;
    }
  }
}

// ---------------- all 8 roles, one dispatch, 16-block barriers (bar[0..6]) ----
__global__ __launch_bounds__(512) void roles_kernel(
    const float* __restrict__ sr_s, const float* __restrict__ sr_m,
    const float* __restrict__ tok_s, const float* __restrict__ ent_m,
    const float* __restrict__ G, const float* __restrict__ betas,
    const float* __restrict__ sb, const float* __restrict__ mb,
    const int* __restrict__ c2t, const int* __restrict__ e2t,
    const int* __restrict__ spans, const int* __restrict__ labels,
    const float* __restrict__ msum, float* __restrict__ out,
    float* __restrict__ xlog, float* __restrict__ PS, int* bar)
{
  __shared__ float pta[S_];
  __shared__ float merged[S_];
  __shared__ float es[E_];
  __shared__ float red[8];
  __shared__ int   spn[E_*P_*2];
  const int b = blockIdx.x;
  const int t = threadIdx.x;
  const int bs = b*S_ + t;
  const int wid = t >> 6, lane = t & 63;

  if (t < E_*P_*2) spn[t] = spans[b*(E_*P_*2) + t];
  const int c_own = c2t[bs];
  const int e_own = e2t[bs];
  const float sb0 = sb[0], mb0 = mb[0];
  const float msumv = msum[0];
  const float tok_sv = tok_s[bs], ent_mv = ent_m[bs];
  float bsum_s = 0.f, bsum_m = 0.f;

  for (int r = 0; r < R_; ++r){
    pta[t] = 0.f;
    if (t < E_) es[t] = 0.f;

    float sl[B_], ml[B_];
    if (r == 0){
      #pragma unroll
      for (int bb = 0; bb < B_; bb++){
        int q = bb*S_ + t;
        sl[bb] = sr_s[q] + tok_s[q] + sb0;
        ml[bb] = sr_m[q] + ent_m[q] + mb0;
      }
    } else {
      const float* xc = xlog + (size_t)(r & 1) * (2*M_);
      #pragma unroll
      for (int bb = 0; bb < B_; bb++){
        sl[bb] = xc[bb*S_ + t];
        ml[bb] = xc[M_ + bb*S_ + t];
      }
    }
    float smax = -1e30f, mmax = -1e30f;
    #pragma unroll
    for (int bb = 0; bb < B_; bb++){ smax = fmaxf(smax, sl[bb]); mmax = fmaxf(mmax, ml[bb]); }
    float ssum = 0.f, msv = 0.f;
    #pragma unroll
    for (int bb = 0; bb < B_; bb++){ ssum += __expf(sl[bb]-smax); msv += __expf(ml[bb]-mmax); }
    float spv = __expf(sl[b]-smax) / ssum;
    float mpv = __expf(ml[b]-mmax) / msv;

    __syncthreads();
    if (c_own >= 0) atomicAdd(&pta[c_own], spv);
    if (e_own >= 0) atomicAdd(&es[e_own], mpv);
    __syncthreads();

    float pei = 0.f;
    #pragma unroll
    for (int e = 0; e < E_; e++){
      float sc = es[e];
      #pragma unroll
      for (int p = 0; p < P_; p++){
        int st = spn[e*8 + p*2], en = spn[e*8 + p*2 + 1];
        if (t >= st && t < en) pei += sc;
      }
    }
    float mg = fmaxf(pta[t], pei);
    merged[t] = mg;
    out[1 + (size_t)r*M_ + bs] = mg;
    __syncthreads();

    float ah_r = (c_own >= 0) ? merged[c_own] : 0.f;

    float mx = mg;
    #pragma unroll
    for (int k = 32; k >= 1; k >>= 1) mx = fmaxf(mx, __shfl_xor(mx, k, 64));
    if (lane == 0) red[wid] = mx;
    __syncthreads();
    float gmx = red[0];
    #pragma unroll
    for (int i = 1; i < 8; i++) gmx = fmaxf(gmx, red[i]);
    float se = __expf(mg - gmx);
    #pragma unroll
    for (int k = 32; k >= 1; k >>= 1) se += __shfl_xor(se, k, 64);
    __syncthreads();
    if (lane == 0) red[wid] = se;
    __syncthreads();
    if (t == 0){
      float tot = 0.f;
      #pragma unroll
      for (int i = 0; i < 8; i++) tot += red[i];
      float lse = gmx + __logf(tot);
      int lbl = labels[r*B_ + b];
      float nll = lse - merged[lbl];
      atomicAdd(out, nll * msumv * (1.0f/16.0f));
    }

    if (r < 7){
      bsum_s += betas[r]; bsum_m += betas[8 + r];
      float ps_next = 0.f, pm_next = 0.f;
      for (int q = r + 1; q <= 7; q++){
        float gs = G[(size_t)(q-1-r)*M_ + bs];
        float gm = G[(size_t)(7 + q-1-r)*M_ + bs];
        float ns = PS[((size_t)q*2 + 0)*M_ + bs] + ah_r * gs;
        float nm = PS[((size_t)q*2 + 1)*M_ + bs] + ah_r * gm;
        PS[((size_t)q*2 + 0)*M_ + bs] = ns;
        PS[((size_t)q*2 + 1)*M_ + bs] = nm;
        if (q == r + 1){ ps_next = ns; pm_next = nm; }
      }
      float xn = sr_s[(size_t)((r+1)*B_ + b)*S_ + t] + tok_sv + ps_next + sb0 + bsum_s;
      float yn = sr_m[(size_t)((r+1)*B_ + b)*S_ + t] + ent_mv + pm_next + mb0 + bsum_m;
      float* xn_buf = xlog + (size_t)((r+1) & 1) * (2*M_);
      xn_buf[bs] = xn;
      xn_buf[M_ + bs] = yn;
      group_barrier(&bar[r], 16);   // separates write from next-role read
    }
  }
}

extern "C" void kernel_launch(void* const* d_in, const int* in_sizes, int n_in,
                              void* d_out, int out_size, void* d_ws, size_t ws_size,
                              hipStream_t stream){
  (void)in_sizes; (void)n_in; (void)out_size; (void)ws_size;
  const int*   labels = (const int*)  d_in[0];
  const float* sr     = (const float*)d_in[1];
  const float* tok    = (const float*)d_in[2];
  const float* ent    = (const float*)d_in[3];
  const float* tmask  = (const float*)d_in[4];
  // d_in[5] entity_mask unused by reference
  const int*   spans  = (const int*)  d_in[6];
  const int*   c2t    = (const int*)  d_in[7];
  const int*   e2t    = (const int*)  d_in[8];
  const float* sw     = (const float*)d_in[9];
  const float* sb     = (const float*)d_in[10];
  const float* mw     = (const float*)d_in[11];
  const float* mb     = (const float*)d_in[12];
  const float* aw     = (const float*)d_in[13];
  const float* ab     = (const float*)d_in[14];
  float* out = (float*)d_out;
  char*  ws  = (char*)d_ws;

  size_t o = 0;
  auto take = [&](size_t bytes){ size_t c = o; o += (bytes + 255) & ~(size_t)255; return c; };
  float* sr_s  = (float*)(ws + take((size_t)R_*B_*S_*4));
  float* sr_m  = (float*)(ws + take((size_t)R_*B_*S_*4));
  float* tok_s = (float*)(ws + take((size_t)B_*S_*4));
  float* ent_m = (float*)(ws + take((size_t)B_*S_*4));
  float* a_s   = (float*)(ws + take((size_t)8*H_*4));
  float* a_m   = (float*)(ws + take((size_t)8*H_*4));
  float* V     = (float*)(ws + take((size_t)14*H_*4));
  float* betas = (float*)(ws + take(64));
  float* G     = (float*)(ws + take((size_t)14*M_*4));
  float* PS    = (float*)(ws + take((size_t)8*2*M_*4));   // zeroed in dots init
  float* xlog  = (float*)(ws + take((size_t)2*2*M_*4));
  float* msum  = (float*)(ws + take(256));
  int*   bar   = (int*)  (ws + take(64));                 // roles barrier counters

  (void)hipMemsetAsync(bar, 0, 64, stream);
  for (int k = 0; k < 7; k++)
    vec_chain_kernel<<<257, 256, 0, stream>>>(k, aw, ab, sw, mw, a_s, a_m, V, betas);
  dots_staged_kernel<<<2048, 256, 0, stream>>>(sr, tok, ent, sw, mw, V, tmask,
                                               sr_s, sr_m, tok_s, ent_m, G, PS, msum, out);
  roles_kernel<<<16, 512, 0, stream>>>(sr_s, sr_m, tok_s, ent_m, G, betas,
                                       sb, mb, c2t, e2t, spans, labels, msum, out,
                                       xlog, PS, bar);
}